// Round 11
// baseline (175.694 us; speedup 1.0000x reference)
//
#include <hip/hip_runtime.h>

#define HID 64
#define TT  128
#define NROWS 8192
#define NGRP (NROWS / 16)   // 512 groups of 16 length-sorted rows
#define LOG2E 1.44269504088896f

typedef _Float16 half8 __attribute__((ext_vector_type(8)));
typedef float    f32x4 __attribute__((ext_vector_type(4)));

// d_ws byte layout
#define WS_WF    0        // 12 tiles * 64 lanes * 8 f16  = 12288 B
#define WS_WHH   12288    // 12 * 2kt * 64 * 8 f16        = 24576 B
#define WS_BA    36864    // 128 f32 fused bias r,z (pre-scaled by log2e)
#define WS_BX    37376    // 64 f32 b_f n-side (pre-scaled by 2log2e)
#define WS_BH    37632    // 64 f32 b_hh n-side (pre-scaled by 2log2e)
#define WS_EMB   37888    // 17*8 f16 embedding rows
#define WS_LROW  38176    // 8192 i32 per-row length
#define WS_ORDER 70944    // 8192 i32 rows sorted ascending by L

// blocks 0..63: per-row lengths (ballot popcount). block 64: weight fusion +
// MFMA A-tile emission + emb table. No atomics, no cross-block protocol.
__global__ __launch_bounds__(256) void prep(
    const float* __restrict__ E_actor, const float* __restrict__ E_action,
    const float* __restrict__ E_street, const float* __restrict__ W_proj,
    const float* __restrict__ b_proj, const float* __restrict__ W_ih,
    const float* __restrict__ b_ih, const float* __restrict__ W_hh,
    const float* __restrict__ b_hh, const int* __restrict__ mask,
    char* __restrict__ ws)
{
    const int j = threadIdx.x;
    if (blockIdx.x != 64) {
        int* Lrow = (int*)(ws + WS_LROW);
        const int wv = j >> 6, ln = j & 63;
        const int r0 = blockIdx.x * 128;
        for (int i = 0; i < 32; i++) {
            const int row = r0 + i * 4 + wv, base = row * TT;
            const int m0 = mask[base + ln], m1 = mask[base + 64 + ln];
            const int L = __popcll(__ballot(m0 != 0)) + __popcll(__ballot(m1 != 0));
            if (ln == 0) Lrow[row] = L;
        }
        return;
    }

    _Float16* WF  = (_Float16*)(ws + WS_WF);
    _Float16* WHH = (_Float16*)(ws + WS_WHH);
    float*    BA  = (float*)(ws + WS_BA);
    float*    BX  = (float*)(ws + WS_BX);
    float*    BH  = (float*)(ws + WS_BH);
    _Float16* EMB = (_Float16*)(ws + WS_EMB);

    __shared__ float wfs[192][32];
    if (j < 192) {
        // W_f[j][m] = sum_k W_ih[j,k]*W_proj[k,m]; b_f = b_ih + W_ih*b_proj
        float wf[21];
        #pragma unroll
        for (int m = 0; m < 21; m++) wf[m] = 0.f;
        float bf = b_ih[j];
        for (int k = 0; k < 32; k++) {
            float w = W_ih[j * 32 + k];
            bf += w * b_proj[k];
            #pragma unroll
            for (int m = 0; m < 21; m++) wf[m] += w * W_proj[k * 21 + m];
        }
        // fold log2e (r,z rows) / 2log2e (n rows): activations become raw exp2
        const float s = (j < 128) ? LOG2E : 2.f * LOG2E;
        #pragma unroll
        for (int m = 0; m < 21; m++) wfs[j][m] = wf[m] * s;
        #pragma unroll
        for (int m = 21; m < 32; m++) wfs[j][m] = 0.f;
        if (j < 128) BA[j] = (bf + b_hh[j]) * LOG2E;
        else { BX[j - 128] = bf * 2.f * LOG2E; BH[j - 128] = b_hh[j] * 2.f * LOG2E; }
    }
    if (j < 17 * 8) {   // emb rows: 0..6 actor, 7..10 action, 11..15 street, 16 zero
        int r = j >> 3, m = j & 7;
        float v = 0.f;
        if (r < 7)       v = E_actor[r * 8 + m];
        else if (r < 11) v = E_action[(r - 7) * 8 + m];
        else if (r < 16) v = (m < 4) ? E_street[(r - 11) * 4 + m] : 0.f;
        EMB[j] = (_Float16)v;
    }
    __syncthreads();

    // A-layout: A[m=lane&15][k=(lane>>4)*8+pos]
    for (int idx = j; idx < 12 * 64; idx += 256) {
        const int T = idx >> 6, lane = idx & 63;
        const int g3 = T >> 2, w = T & 3, m16 = lane & 15, kq = lane >> 4;
        const int jr = g3 * 64 + w * 16 + m16;
        _Float16 v[8];
        #pragma unroll
        for (int m = 0; m < 8; m++) v[m] = (_Float16)wfs[jr][kq * 8 + m];
        *(uint4*)&WF[idx * 8] = *(uint4*)v;
    }
    for (int idx = j; idx < 12 * 2 * 64; idx += 256) {
        const int T = idx >> 7, rem = idx & 127, kt = rem >> 6, lane = rem & 63;
        const int g3 = T >> 2, w = T & 3, m16 = lane & 15, kq = lane >> 4;
        const int jr = g3 * 64 + w * 16 + m16;
        const int kbase = kt * 32 + kq * 8;
        const float s = (jr < 128) ? LOG2E : 2.f * LOG2E;
        _Float16 v[8];
        #pragma unroll
        for (int m = 0; m < 8; m++) v[m] = (_Float16)(W_hh[jr * HID + kbase + m] * s);
        *(uint4*)&WHH[((T * 2 + kt) * 64 + lane) * 8] = *(uint4*)v;
    }
}

// One block: LDS histogram + register ranks + serial 129-scan + scatter.
__global__ __launch_bounds__(256) void sort_rows(
    const int* __restrict__ Lrow, int* __restrict__ order)
{
    __shared__ int hist[TT + 1];
    __shared__ int pref[TT + 1];
    const int tid = threadIdx.x;
    if (tid <= TT) hist[tid] = 0;
    __syncthreads();
    int rnk[NROWS / 256], Ls[NROWS / 256];
    #pragma unroll 4
    for (int i = 0; i < NROWS / 256; i++) {
        const int r = i * 256 + tid;
        const int L = Lrow[r];
        Ls[i] = L;
        rnk[i] = atomicAdd(&hist[L], 1);
    }
    __syncthreads();
    if (tid == 0) {
        int run = 0;
        for (int i = 0; i <= TT; i++) { pref[i] = run; run += hist[i]; }
    }
    __syncthreads();
    #pragma unroll 4
    for (int i = 0; i < NROWS / 256; i++) {
        const int r = i * 256 + tid;
        order[pref[Ls[i]] + rnk[i]] = r;
    }
}

// One 256-thread block (4 waves) per 16-row length-sorted group; wave wv owns
// hid quarter [16wv,16wv+16) = M-tiles {wv,4+wv,8+wv}. Per step: 6 h-side
// MFMA (K-tiles chained through C: no merge adds) + 3 x-side MFMA prefetched
// for t+1. Weights pre-scaled by log2e/2log2e -> raw exp2 activations.
// fp32 h master in regs, f16 LDS copy double-buffered. Sorted groups keep
// Lmax ~= Lavg per block; long/short block pairing gives tail blocks a quiet CU.
__global__ __launch_bounds__(256, 2) void gru_mfma(
    const int* __restrict__ actor_ids, const int* __restrict__ action_ids,
    const int* __restrict__ street_ids, const float* __restrict__ bet,
    const char* __restrict__ ws, const int* __restrict__ order,
    const int* __restrict__ Lrow, float* __restrict__ out)
{
    const _Float16* WF  = (const _Float16*)(ws + WS_WF);
    const _Float16* WHH = (const _Float16*)(ws + WS_WHH);
    const float*    BA  = (const float*)(ws + WS_BA);
    const float*    BX  = (const float*)(ws + WS_BX);
    const float*    BH  = (const float*)(ws + WS_BH);
    const _Float16* EMB = (const _Float16*)(ws + WS_EMB);

    __shared__ int pb[TT][17];                        // ids|bet16, padded
    __shared__ __align__(16) _Float16 hb[2][16][72];  // stride 72: 2-way max (free)
    __shared__ __align__(16) _Float16 embl[144];

    const int tid = threadIdx.x;
    const int wv  = tid >> 6;        // wave = hid quarter
    const int l   = tid & 63;
    const int q   = l >> 4;          // quad
    const int n   = l & 15;          // batch col within group

    const int b = blockIdx.x;
    const int g = (b & 1) ? (NGRP - 1 - (b >> 1)) : (b >> 1);

    for (int i = tid; i < 136; i += 256) embl[i] = EMB[i];
    for (int i = tid; i < 2 * 16 * 72 / 2; i += 256) ((int*)hb)[i] = 0;
    {   // stage packed ids+bet16: 16 thr/row, 8 t/thr
        const int r = tid >> 4, tl = tid & 15;
        const int rowr = order[g * 16 + r];
        const int base = rowr * TT;
        #pragma unroll
        for (int i = 0; i < 8; i++) {
            const int t = tl + 16 * i;
            const int a = actor_ids[base + t], c = action_ids[base + t];
            const int s = street_ids[base + t];
            const _Float16 f16 = (_Float16)bet[base + t];
            const unsigned fb = (unsigned)*(const unsigned short*)&f16;
            pb[t][r] = (int)(a | (c << 3) | (s << 5) | (fb << 16));
        }
    }

    // loop-invariant A-fragments (AGPR-resident is fine for MFMA operands)
    half8 Af[3], Ah[3][2];
    #pragma unroll
    for (int g3 = 0; g3 < 3; g3++) {
        const int T = g3 * 4 + wv;
        Af[g3]    = *(const half8*)&WF[(T * 64 + l) * 8];
        Ah[g3][0] = *(const half8*)&WHH[((T * 2 + 0) * 64 + l) * 8];
        Ah[g3][1] = *(const half8*)&WHH[((T * 2 + 1) * 64 + l) * 8];
    }
    f32x4 biasR, biasZ, biasX, biasH;
    #pragma unroll
    for (int e = 0; e < 4; e++) {
        const int idx = 16 * wv + 4 * q + e;
        biasR[e] = BA[idx];
        biasZ[e] = BA[64 + idx];
        biasX[e] = BX[idx];
        biasH[e] = BH[idx];
    }

    const int myrow = order[g * 16 + n];
    const int Ln    = Lrow[myrow];
    const int Lmax  = __shfl(Ln, 15);   // ascending sort -> n=15 holds max
    const bool isq2 = (q == 2);
    // per-lane constant field extractor: eidx = ((p>>sh)&mk)+of
    const int sh = (q == 1) ? 3 : (q == 2) ? 5 : 0;
    const int mk = (q == 1) ? 3 : (q == 3) ? 0 : 7;
    const int of = (q == 1) ? 7 : (q == 2) ? 11 : (q == 3) ? 16 : 0;

    float h[4] = {0.f, 0.f, 0.f, 0.f};

    __syncthreads();   // pb/hb/embl visible

    // prime step-0 x-side accumulators
    f32x4 xR, xZ, xX;
    {
        const int p = pb[0][n];
        const int eidx = ((p >> sh) & mk) + of;
        half8 Bf = *(const half8*)&embl[eidx * 8];
        uint4* bu = (uint4*)&Bf;
        bu->z = isq2 ? ((unsigned)p >> 16) : bu->z;   // {bet16, 0} at k=20,21
        xR = __builtin_amdgcn_mfma_f32_16x16x32_f16(Af[0], Bf, biasR, 0, 0, 0);
        xZ = __builtin_amdgcn_mfma_f32_16x16x32_f16(Af[1], Bf, biasZ, 0, 0, 0);
        xX = __builtin_amdgcn_mfma_f32_16x16x32_f16(Af[2], Bf, biasX, 0, 0, 0);
    }

    for (int t = 0; t < Lmax; t++) {
        const int buf = t & 1;
        const half8 Bh0 = *(const half8*)&hb[buf][n][q * 8];
        const half8 Bh1 = *(const half8*)&hb[buf][n][32 + q * 8];
        // K-tiles chained through the C operand (3 independent depth-2 chains)
        f32x4 aR = __builtin_amdgcn_mfma_f32_16x16x32_f16(Ah[0][0], Bh0, xR, 0, 0, 0);
        aR = __builtin_amdgcn_mfma_f32_16x16x32_f16(Ah[0][1], Bh1, aR, 0, 0, 0);
        f32x4 aZ = __builtin_amdgcn_mfma_f32_16x16x32_f16(Ah[1][0], Bh0, xZ, 0, 0, 0);
        aZ = __builtin_amdgcn_mfma_f32_16x16x32_f16(Ah[1][1], Bh1, aZ, 0, 0, 0);
        f32x4 aH = __builtin_amdgcn_mfma_f32_16x16x32_f16(Ah[2][0], Bh0, biasH, 0, 0, 0);
        aH = __builtin_amdgcn_mfma_f32_16x16x32_f16(Ah[2][1], Bh1, aH, 0, 0, 0);
        const f32x4 aXc = xX;

        // prefetch step t+1 x-side (independent of this step's h)
        {
            const int tn = (t + 1 < TT) ? t + 1 : TT - 1;
            const int p = pb[tn][n];
            const int eidx = ((p >> sh) & mk) + of;
            half8 Bf = *(const half8*)&embl[eidx * 8];
            uint4* bu = (uint4*)&Bf;
            bu->z = isq2 ? ((unsigned)p >> 16) : bu->z;
            xR = __builtin_amdgcn_mfma_f32_16x16x32_f16(Af[0], Bf, biasR, 0, 0, 0);
            xZ = __builtin_amdgcn_mfma_f32_16x16x32_f16(Af[1], Bf, biasZ, 0, 0, 0);
            xX = __builtin_amdgcn_mfma_f32_16x16x32_f16(Af[2], Bf, biasX, 0, 0, 0);
        }

        const bool live = (t < Ln);
        _Float16 hp[4];
        #pragma unroll
        for (int e = 0; e < 4; e++) {
            // weights pre-scaled: aR,aZ in log2 domain; aX,aH in 2log2e domain
            const float r = __builtin_amdgcn_rcpf(1.f + __builtin_amdgcn_exp2f(-aR[e]));
            const float z = __builtin_amdgcn_rcpf(1.f + __builtin_amdgcn_exp2f(-aZ[e]));
            const float y2 = aXc[e] + r * aH[e];           // = 2*log2e*y
            const float nn = 1.f - 2.f * __builtin_amdgcn_rcpf(1.f + __builtin_amdgcn_exp2f(y2));
            const float hv = nn + z * (h[e] - nn);
            h[e] = live ? hv : h[e];
            hp[e] = (_Float16)h[e];
        }
        *(uint2*)&hb[buf ^ 1][n][16 * wv + 4 * q] = *(uint2*)hp;
        __syncthreads();
    }

    float4 o = make_float4(h[0], h[1], h[2], h[3]);
    *(float4*)&out[myrow * HID + 16 * wv + 4 * q] = o;
}

extern "C" void kernel_launch(void* const* d_in, const int* in_sizes, int n_in,
                              void* d_out, int out_size, void* d_ws, size_t ws_size,
                              hipStream_t stream) {
    const int*   actor_ids  = (const int*)d_in[0];
    const int*   action_ids = (const int*)d_in[1];
    const int*   street_ids = (const int*)d_in[2];
    const float* bet        = (const float*)d_in[3];
    const int*   vmask      = (const int*)d_in[4];
    const float* E_actor    = (const float*)d_in[5];
    const float* E_action   = (const float*)d_in[6];
    const float* E_street   = (const float*)d_in[7];
    const float* W_proj     = (const float*)d_in[8];
    const float* b_proj     = (const float*)d_in[9];
    const float* W_ih       = (const float*)d_in[10];
    const float* W_hh       = (const float*)d_in[11];
    const float* b_ih       = (const float*)d_in[12];
    const float* b_hh       = (const float*)d_in[13];
    float*       out        = (float*)d_out;

    char* ws = (char*)d_ws;
    int*  Lrow  = (int*)(ws + WS_LROW);
    int*  order = (int*)(ws + WS_ORDER);

    prep<<<65, 256, 0, stream>>>(E_actor, E_action, E_street, W_proj, b_proj,
                                 W_ih, b_ih, W_hh, b_hh, vmask, ws);
    sort_rows<<<1, 256, 0, stream>>>(Lrow, order);
    gru_mfma<<<NGRP, 256, 0, stream>>>(actor_ids, action_ids, street_ids, bet,
                                       ws, order, Lrow, out);
}